// Round 1
// baseline (704.443 us; speedup 1.0000x reference)
//
#include <hip/hip_runtime.h>
#include <hip/hip_bf16.h>
#include <climits>

#define N_NODES 50000
#define N_EDGES 800000
#define FDIM 128
#define HID 64
#define NPERM 128
#define HLLM 64

// ---------------- degree / CSR build ----------------

__global__ void k_init_deg(int* deg) {
    int i = blockIdx.x * blockDim.x + threadIdx.x;
    if (i < N_NODES) deg[i] = 1;  // self loop
}

__global__ void k_count_deg(const int* __restrict__ dst, int* __restrict__ deg) {
    int e = blockIdx.x * blockDim.x + threadIdx.x;
    if (e < N_EDGES) atomicAdd(&deg[dst[e]], 1);
}

// single-block exclusive scan over N_NODES degrees -> offsets[N_NODES+1]
__global__ void k_scan(const int* __restrict__ deg, int* __restrict__ offsets) {
    __shared__ int sdata[1024];
    __shared__ int carry_s;
    if (threadIdx.x == 0) carry_s = 0;
    __syncthreads();
    for (int base = 0; base < N_NODES; base += 1024) {
        int i = base + threadIdx.x;
        int v = (i < N_NODES) ? deg[i] : 0;
        sdata[threadIdx.x] = v;
        __syncthreads();
        for (int off = 1; off < 1024; off <<= 1) {
            int t = (threadIdx.x >= off) ? sdata[threadIdx.x - off] : 0;
            __syncthreads();
            sdata[threadIdx.x] += t;
            __syncthreads();
        }
        if (i < N_NODES) offsets[i] = carry_s + sdata[threadIdx.x] - v;  // exclusive
        __syncthreads();
        if (threadIdx.x == 1023) carry_s += sdata[1023];
        __syncthreads();
    }
    if (threadIdx.x == 0) offsets[N_NODES] = carry_s;
}

// dis = rsqrt(deg); place self-loop at slot offsets[i]; cursor starts after it
__global__ void k_dis_cursor(const int* __restrict__ deg, const int* __restrict__ offsets,
                             float* __restrict__ dis, int* __restrict__ cursor,
                             int* __restrict__ csr) {
    int i = blockIdx.x * blockDim.x + threadIdx.x;
    if (i < N_NODES) {
        dis[i] = rsqrtf((float)deg[i]);
        int o = offsets[i];
        csr[o] = i;
        cursor[i] = o + 1;
    }
}

__global__ void k_fill(const int* __restrict__ src, const int* __restrict__ dst,
                       int* __restrict__ cursor, int* __restrict__ csr) {
    int e = blockIdx.x * blockDim.x + threadIdx.x;
    if (e < N_EDGES) {
        int p = atomicAdd(&cursor[dst[e]], 1);
        csr[p] = src[e];
    }
}

// ---------------- dense GEMMs ----------------

// h = x @ W_enc + b_enc   (50000x128 @ 128x64)
__global__ void k_encoder(const float* __restrict__ x, const float* __restrict__ W,
                          const float* __restrict__ b, float* __restrict__ h) {
    __shared__ float Ws[FDIM * HID];  // 32 KB
    for (int idx = threadIdx.x; idx < FDIM * HID; idx += 256) Ws[idx] = W[idx];
    __syncthreads();
    int row = blockIdx.x * 64 + (threadIdx.x >> 2);
    int c0 = (threadIdx.x & 3) * 16;
    if (row >= N_NODES) return;
    float acc[16];
#pragma unroll
    for (int j = 0; j < 16; ++j) acc[j] = b[c0 + j];
    const float* xr = x + (size_t)row * FDIM;
    for (int k = 0; k < FDIM; ++k) {
        float xv = xr[k];
        const float* wr = Ws + k * HID + c0;
#pragma unroll
        for (int j = 0; j < 16; ++j) acc[j] = fmaf(xv, wr[j], acc[j]);
    }
    float* hr = h + (size_t)row * HID + c0;
#pragma unroll
    for (int j = 0; j < 16; ++j) hr[j] = acc[j];
}

// hWs = dis ⊙ (h @ W_k)   (50000x64 @ 64x64, rows scaled by dis)
__global__ void k_convmm(const float* __restrict__ h, const float* __restrict__ W,
                         const float* __restrict__ dis, float* __restrict__ hWs) {
    __shared__ float Ws[HID * HID];  // 16 KB
    for (int idx = threadIdx.x; idx < HID * HID; idx += 256) Ws[idx] = W[idx];
    __syncthreads();
    int row = blockIdx.x * 64 + (threadIdx.x >> 2);
    int c0 = (threadIdx.x & 3) * 16;
    if (row >= N_NODES) return;
    float acc[16] = {0.f, 0.f, 0.f, 0.f, 0.f, 0.f, 0.f, 0.f,
                     0.f, 0.f, 0.f, 0.f, 0.f, 0.f, 0.f, 0.f};
    const float* hr = h + (size_t)row * HID;
    for (int k = 0; k < HID; ++k) {
        float hv = hr[k];
        const float* wr = Ws + k * HID + c0;
#pragma unroll
        for (int j = 0; j < 16; ++j) acc[j] = fmaf(hv, wr[j], acc[j]);
    }
    float d = dis[row];
    float* o = hWs + (size_t)row * HID + c0;
#pragma unroll
    for (int j = 0; j < 16; ++j) o[j] = d * acc[j];
}

// ---------------- hash propagation (gather over CSR) ----------------

// HLL: per-node register-wise max over in-neighborhood (incl self).
// One 64-lane wave per node, lane = register. Also emits cardinality.
__global__ void k_hll(const int* __restrict__ offsets, const int* __restrict__ csr,
                      const int* __restrict__ hin, int* __restrict__ hout_i,
                      float* __restrict__ hout_f, float* __restrict__ cards, int kcol) {
    int node = blockIdx.x * 4 + (threadIdx.x >> 6);
    int r = threadIdx.x & 63;
    if (node >= N_NODES) return;
    int s = offsets[node], e = offsets[node + 1];
    int mx = INT_MIN;
    for (int p = s; p < e; ++p) {
        int j = csr[p];
        mx = max(mx, hin[(size_t)j * HLLM + r]);
    }
    if (hout_i) hout_i[(size_t)node * HLLM + r] = mx;
    if (hout_f) hout_f[(size_t)node * HLLM + r] = (float)mx;
    float v = exp2f(-(float)mx);
#pragma unroll
    for (int off = 32; off >= 1; off >>= 1) v += __shfl_xor(v, off);
    if (r == 0) {
        const float alphamm = (float)(0.7213 / (1.0 + 1.079 / 64.0) * 64.0 * 64.0);
        cards[(size_t)node * 2 + kcol] = alphamm / v;
    }
}

// minhash: per-node permutation-wise min. 128 threads (2 waves) per node.
__global__ void k_mh(const int* __restrict__ offsets, const int* __restrict__ csr,
                     const int* __restrict__ min_in, int* __restrict__ out_i,
                     float* __restrict__ out_f) {
    int node = blockIdx.x * 2 + (threadIdx.x >> 7);
    int r = threadIdx.x & 127;
    if (node >= N_NODES) return;
    int s = offsets[node], e = offsets[node + 1];
    int mn = INT_MAX;
    for (int p = s; p < e; ++p) {
        int j = csr[p];
        mn = min(mn, min_in[(size_t)j * NPERM + r]);
    }
    if (out_i) out_i[(size_t)node * NPERM + r] = mn;
    else       out_f[(size_t)node * NPERM + r] = (float)mn;
}

// GCN aggregate: h_out[i] = h_in[i] + b + dis[i] * sum_{j in in(i)} hWs[j]
__global__ void k_agg(const int* __restrict__ offsets, const int* __restrict__ csr,
                      const float* __restrict__ hWs, const float* __restrict__ dis,
                      const float* __restrict__ b, const float* __restrict__ h_in,
                      float* __restrict__ h_out) {
    int node = blockIdx.x * 4 + (threadIdx.x >> 6);
    int c = threadIdx.x & 63;
    if (node >= N_NODES) return;
    int s = offsets[node], e = offsets[node + 1];
    float acc = 0.f;
    for (int p = s; p < e; ++p) {
        int j = csr[p];
        acc += hWs[(size_t)j * HID + c];
    }
    h_out[(size_t)node * HID + c] = h_in[(size_t)node * HID + c] + b[c] + dis[node] * acc;
}

// ---------------- driver ----------------

extern "C" void kernel_launch(void* const* d_in, const int* in_sizes, int n_in,
                              void* d_out, int out_size, void* d_ws, size_t ws_size,
                              hipStream_t stream) {
    const float* x       = (const float*)d_in[0];
    const int*   ei      = (const int*)d_in[1];
    const int*   mh0     = (const int*)d_in[2];
    const int*   hll0    = (const int*)d_in[3];
    const float* W_enc   = (const float*)d_in[4];
    const float* b_enc   = (const float*)d_in[5];
    const float* W_convs = (const float*)d_in[6];
    const float* b_convs = (const float*)d_in[7];

    float* out       = (float*)d_out;
    float* out_h     = out;                                   // N*64
    float* out_cards = out + (size_t)N_NODES * HID;           // N*2
    float* out_mh    = out_cards + (size_t)N_NODES * 2;       // N*128
    float* out_hll   = out_mh + (size_t)N_NODES * NPERM;      // N*64

    char* w = (char*)d_ws;
    int*   deg     = (int*)w;   w += (size_t)N_NODES * 4;
    int*   offsets = (int*)w;   w += (size_t)(N_NODES + 1) * 4;
    int*   cursor  = (int*)w;   w += (size_t)N_NODES * 4;
    float* dis     = (float*)w; w += (size_t)N_NODES * 4;
    int*   csr     = (int*)w;   w += (size_t)(N_EDGES + N_NODES) * 4;
    int*   mhA     = (int*)w;   w += (size_t)N_NODES * NPERM * 4;
    int*   hllA    = (int*)w;   w += (size_t)N_NODES * HLLM * 4;
    float* h_cur   = (float*)w; w += (size_t)N_NODES * HID * 4;
    float* hWs     = (float*)w; w += (size_t)N_NODES * HID * 4;

    const int* src = ei;
    const int* dst = ei + N_EDGES;

    k_init_deg<<<(N_NODES + 255) / 256, 256, 0, stream>>>(deg);
    k_count_deg<<<(N_EDGES + 255) / 256, 256, 0, stream>>>(dst, deg);
    k_scan<<<1, 1024, 0, stream>>>(deg, offsets);
    k_dis_cursor<<<(N_NODES + 255) / 256, 256, 0, stream>>>(deg, offsets, dis, cursor, csr);
    k_fill<<<(N_EDGES + 255) / 256, 256, 0, stream>>>(src, dst, cursor, csr);
    k_encoder<<<(N_NODES + 63) / 64, 256, 0, stream>>>(x, W_enc, b_enc, h_cur);

    // ---- hop 0 ----
    k_hll<<<(N_NODES + 3) / 4, 256, 0, stream>>>(offsets, csr, hll0, hllA, nullptr, out_cards, 0);
    k_mh<<<(N_NODES + 1) / 2, 256, 0, stream>>>(offsets, csr, mh0, mhA, nullptr);
    k_convmm<<<(N_NODES + 63) / 64, 256, 0, stream>>>(h_cur, W_convs, dis, hWs);
    k_agg<<<(N_NODES + 3) / 4, 256, 0, stream>>>(offsets, csr, hWs, dis, b_convs, h_cur, h_cur);

    // ---- hop 1 ----
    k_hll<<<(N_NODES + 3) / 4, 256, 0, stream>>>(offsets, csr, hllA, nullptr, out_hll, out_cards, 1);
    k_mh<<<(N_NODES + 1) / 2, 256, 0, stream>>>(offsets, csr, mhA, nullptr, out_mh);
    k_convmm<<<(N_NODES + 63) / 64, 256, 0, stream>>>(h_cur, W_convs + HID * HID, dis, hWs);
    k_agg<<<(N_NODES + 3) / 4, 256, 0, stream>>>(offsets, csr, hWs, dis, b_convs + HID, h_cur, out_h);
}

// Round 2
// 400.458 us; speedup vs baseline: 1.7591x; 1.7591x over previous
//
#include <hip/hip_runtime.h>
#include <hip/hip_bf16.h>
#include <climits>

typedef unsigned int uint;

#define N_NODES 50000
#define N_EDGES 800000
#define FDIM 128
#define HID 64
#define NPERM 128
#define HLLM 64

// ---------------- degree / CSR build ----------------

__global__ void k_init_deg(int* deg) {
    int i = blockIdx.x * blockDim.x + threadIdx.x;
    if (i < N_NODES) deg[i] = 1;  // self loop
}

__global__ void k_count_deg(const int* __restrict__ dst, int* __restrict__ deg) {
    int e = blockIdx.x * blockDim.x + threadIdx.x;
    if (e < N_EDGES) atomicAdd(&deg[dst[e]], 1);
}

// 1-block chunked exclusive scan: thread t owns 49 contiguous nodes.
#define SCAN_CHUNK 49  // ceil(50000/1024)
__global__ void k_scan(const int* __restrict__ deg, int* __restrict__ offsets) {
    __shared__ int part[1024];
    int t = threadIdx.x;
    int lo = t * SCAN_CHUNK;
    int hi = min(lo + SCAN_CHUNK, N_NODES);
    int sum = 0;
    for (int i = lo; i < hi; ++i) sum += deg[i];
    part[t] = sum;
    __syncthreads();
    for (int off = 1; off < 1024; off <<= 1) {
        int v = (t >= off) ? part[t - off] : 0;
        __syncthreads();
        part[t] += v;
        __syncthreads();
    }
    int base = part[t] - sum;  // exclusive prefix of this chunk
    for (int i = lo; i < hi; ++i) { offsets[i] = base; base += deg[i]; }
    if (t == 1023) offsets[N_NODES] = part[1023];
}

__global__ void k_dis_cursor(const int* __restrict__ deg, const int* __restrict__ offsets,
                             float* __restrict__ dis, int* __restrict__ cursor,
                             int* __restrict__ csr) {
    int i = blockIdx.x * blockDim.x + threadIdx.x;
    if (i < N_NODES) {
        dis[i] = rsqrtf((float)deg[i]);
        int o = offsets[i];
        csr[o] = i;           // self-loop first
        cursor[i] = o + 1;
    }
}

__global__ void k_fill(const int* __restrict__ src, const int* __restrict__ dst,
                       int* __restrict__ cursor, int* __restrict__ csr) {
    int e = blockIdx.x * blockDim.x + threadIdx.x;
    if (e < N_EDGES) {
        int p = atomicAdd(&cursor[dst[e]], 1);
        csr[p] = src[e];
    }
}

// ---------------- packing ----------------

// minhash int32 -> top 16 bits of float32 (monotone, error <= |v|/128)
__global__ void k_pack_mh(const int* __restrict__ mh, uint* __restrict__ mhp) {
    int i = blockIdx.x * 256 + threadIdx.x;
    if (i >= N_NODES * (NPERM / 2)) return;
    int2 v = ((const int2*)mh)[i];
    uint u0 = __float_as_uint((float)v.x) >> 16;
    uint u1 = __float_as_uint((float)v.y) >> 16;
    mhp[i] = u0 | (u1 << 16);
}

// hll int32 (<20, max-only so stays <256) -> u8
__global__ void k_pack_hll(const int* __restrict__ hll, uint* __restrict__ hp) {
    int i = blockIdx.x * 256 + threadIdx.x;
    if (i >= N_NODES * (HLLM / 4)) return;
    int4 v = ((const int4*)hll)[i];
    hp[i] = (uint)v.x | ((uint)v.y << 8) | ((uint)v.z << 16) | ((uint)v.w << 24);
}

// ---------------- dense GEMMs ----------------

__global__ void k_encoder(const float* __restrict__ x, const float* __restrict__ W,
                          const float* __restrict__ b, float* __restrict__ h) {
    __shared__ float Ws[FDIM * HID];  // 32 KB
    for (int idx = threadIdx.x; idx < FDIM * HID; idx += 256) Ws[idx] = W[idx];
    __syncthreads();
    int row = blockIdx.x * 64 + (threadIdx.x >> 2);
    int c0 = (threadIdx.x & 3) * 16;
    if (row >= N_NODES) return;
    float acc[16];
#pragma unroll
    for (int j = 0; j < 16; ++j) acc[j] = b[c0 + j];
    const float4* xr = (const float4*)(x + (size_t)row * FDIM);
    for (int k4 = 0; k4 < FDIM / 4; ++k4) {
        float4 xv = xr[k4];
        const float* wr = Ws + (k4 * 4) * HID + c0;
#pragma unroll
        for (int j = 0; j < 16; ++j) acc[j] = fmaf(xv.x, wr[j], acc[j]);
#pragma unroll
        for (int j = 0; j < 16; ++j) acc[j] = fmaf(xv.y, wr[HID + j], acc[j]);
#pragma unroll
        for (int j = 0; j < 16; ++j) acc[j] = fmaf(xv.z, wr[2 * HID + j], acc[j]);
#pragma unroll
        for (int j = 0; j < 16; ++j) acc[j] = fmaf(xv.w, wr[3 * HID + j], acc[j]);
    }
    float* hr = h + (size_t)row * HID + c0;
#pragma unroll
    for (int j = 0; j < 16; ++j) hr[j] = acc[j];
}

// hWs = bf16( dis ⊙ (h @ W_k) )
__global__ void k_convmm(const float* __restrict__ h, const float* __restrict__ W,
                         const float* __restrict__ dis, __hip_bfloat16* __restrict__ hWs) {
    __shared__ float Ws[HID * HID];  // 16 KB
    for (int idx = threadIdx.x; idx < HID * HID; idx += 256) Ws[idx] = W[idx];
    __syncthreads();
    int row = blockIdx.x * 64 + (threadIdx.x >> 2);
    int c0 = (threadIdx.x & 3) * 16;
    if (row >= N_NODES) return;
    float acc[16] = {0.f, 0.f, 0.f, 0.f, 0.f, 0.f, 0.f, 0.f,
                     0.f, 0.f, 0.f, 0.f, 0.f, 0.f, 0.f, 0.f};
    const float4* hr = (const float4*)(h + (size_t)row * HID);
    for (int k4 = 0; k4 < HID / 4; ++k4) {
        float4 hv = hr[k4];
        const float* wr = Ws + (k4 * 4) * HID + c0;
#pragma unroll
        for (int j = 0; j < 16; ++j) acc[j] = fmaf(hv.x, wr[j], acc[j]);
#pragma unroll
        for (int j = 0; j < 16; ++j) acc[j] = fmaf(hv.y, wr[HID + j], acc[j]);
#pragma unroll
        for (int j = 0; j < 16; ++j) acc[j] = fmaf(hv.z, wr[2 * HID + j], acc[j]);
#pragma unroll
        for (int j = 0; j < 16; ++j) acc[j] = fmaf(hv.w, wr[3 * HID + j], acc[j]);
    }
    float d = dis[row];
    __hip_bfloat16* o = hWs + (size_t)row * HID + c0;
#pragma unroll
    for (int j = 0; j < 16; ++j) o[j] = __float2bfloat16(d * acc[j]);
}

// ---------------- hash propagation (gather over CSR, unroll-4) ----------------

// HLL packed u8: 16 lanes per node (4 regs/lane), 16 nodes per 256-block.
__global__ void k_hll(const int* __restrict__ offsets, const int* __restrict__ csr,
                      const uint* __restrict__ hin, uint* __restrict__ hout_p,
                      float* __restrict__ hout_f, float* __restrict__ cards, int kcol) {
    int node = blockIdx.x * 16 + (threadIdx.x >> 4);
    int q = threadIdx.x & 15;
    if (node >= N_NODES) return;
    int s = offsets[node], e = offsets[node + 1];
    uint m0 = 0, m1 = 0, m2 = 0, m3 = 0;
#define HLL_ACC(vv) do { uint _v = (vv); \
        m0 = max(m0, _v & 0xFFu); m1 = max(m1, (_v >> 8) & 0xFFu); \
        m2 = max(m2, (_v >> 16) & 0xFFu); m3 = max(m3, _v >> 24); } while (0)
    int p = s;
    for (; p + 4 <= e; p += 4) {
        int j0 = csr[p], j1 = csr[p + 1], j2 = csr[p + 2], j3 = csr[p + 3];
        uint a = hin[(size_t)j0 * 16 + q];
        uint b = hin[(size_t)j1 * 16 + q];
        uint c = hin[(size_t)j2 * 16 + q];
        uint d = hin[(size_t)j3 * 16 + q];
        HLL_ACC(a); HLL_ACC(b); HLL_ACC(c); HLL_ACC(d);
    }
    for (; p < e; ++p) HLL_ACC(hin[(size_t)csr[p] * 16 + q]);
#undef HLL_ACC
    if (hout_p) hout_p[(size_t)node * 16 + q] = m0 | (m1 << 8) | (m2 << 16) | (m3 << 24);
    if (hout_f) {
        float4 w = {(float)m0, (float)m1, (float)m2, (float)m3};
        *(float4*)(hout_f + (size_t)node * HLLM + 4 * q) = w;
    }
    float v = exp2f(-(float)m0) + exp2f(-(float)m1) + exp2f(-(float)m2) + exp2f(-(float)m3);
    v += __shfl_xor(v, 1); v += __shfl_xor(v, 2);
    v += __shfl_xor(v, 4); v += __shfl_xor(v, 8);
    if (q == 0) {
        const float alphamm = (float)(0.7213 / (1.0 + 1.079 / 64.0) * 64.0 * 64.0);
        cards[(size_t)node * 2 + kcol] = alphamm / v;
    }
}

// minhash packed u16: one wave per node, lane = uint chunk (perms 2l, 2l+1).
__global__ void k_mh(const int* __restrict__ offsets, const int* __restrict__ csr,
                     const uint* __restrict__ mhin, uint* __restrict__ out_p,
                     float* __restrict__ out_f) {
    int node = blockIdx.x * 4 + (threadIdx.x >> 6);
    int l = threadIdx.x & 63;
    if (node >= N_NODES) return;
    int s = offsets[node], e = offsets[node + 1];
    uint mn0 = 0xFFFFu, mn1 = 0xFFFFu;
    int p = s;
    for (; p + 4 <= e; p += 4) {
        int j0 = csr[p], j1 = csr[p + 1], j2 = csr[p + 2], j3 = csr[p + 3];
        uint a = mhin[(size_t)j0 * 64 + l];
        uint b = mhin[(size_t)j1 * 64 + l];
        uint c = mhin[(size_t)j2 * 64 + l];
        uint d = mhin[(size_t)j3 * 64 + l];
        mn0 = min(mn0, a & 0xFFFFu); mn1 = min(mn1, a >> 16);
        mn0 = min(mn0, b & 0xFFFFu); mn1 = min(mn1, b >> 16);
        mn0 = min(mn0, c & 0xFFFFu); mn1 = min(mn1, c >> 16);
        mn0 = min(mn0, d & 0xFFFFu); mn1 = min(mn1, d >> 16);
    }
    for (; p < e; ++p) {
        uint a = mhin[(size_t)csr[p] * 64 + l];
        mn0 = min(mn0, a & 0xFFFFu); mn1 = min(mn1, a >> 16);
    }
    if (out_p) {
        out_p[(size_t)node * 64 + l] = mn0 | (mn1 << 16);
    } else {
        float2 w;
        w.x = __uint_as_float(mn0 << 16);
        w.y = __uint_as_float(mn1 << 16);
        *(float2*)(out_f + (size_t)node * NPERM + 2 * l) = w;
    }
}

// GCN aggregate over bf16 hWs rows (128 B = one cache line per row).
__global__ void k_agg(const int* __restrict__ offsets, const int* __restrict__ csr,
                      const __hip_bfloat16* __restrict__ hWs, const float* __restrict__ dis,
                      const float* __restrict__ b, const float* __restrict__ h_in,
                      float* __restrict__ h_out) {
    int node = blockIdx.x * 4 + (threadIdx.x >> 6);
    int c = threadIdx.x & 63;
    if (node >= N_NODES) return;
    int s = offsets[node], e = offsets[node + 1];
    float acc = 0.f;
    int p = s;
    for (; p + 4 <= e; p += 4) {
        int j0 = csr[p], j1 = csr[p + 1], j2 = csr[p + 2], j3 = csr[p + 3];
        float a = __bfloat162float(hWs[(size_t)j0 * HID + c]);
        float bb = __bfloat162float(hWs[(size_t)j1 * HID + c]);
        float cc = __bfloat162float(hWs[(size_t)j2 * HID + c]);
        float dd = __bfloat162float(hWs[(size_t)j3 * HID + c]);
        acc += a + bb + cc + dd;
    }
    for (; p < e; ++p) acc += __bfloat162float(hWs[(size_t)csr[p] * HID + c]);
    h_out[(size_t)node * HID + c] = h_in[(size_t)node * HID + c] + b[c] + dis[node] * acc;
}

// ---------------- driver ----------------

static inline char* align256(char* p) {
    return (char*)(((uintptr_t)p + 255) & ~(uintptr_t)255);
}

extern "C" void kernel_launch(void* const* d_in, const int* in_sizes, int n_in,
                              void* d_out, int out_size, void* d_ws, size_t ws_size,
                              hipStream_t stream) {
    const float* x       = (const float*)d_in[0];
    const int*   ei      = (const int*)d_in[1];
    const int*   mh0     = (const int*)d_in[2];
    const int*   hll0    = (const int*)d_in[3];
    const float* W_enc   = (const float*)d_in[4];
    const float* b_enc   = (const float*)d_in[5];
    const float* W_convs = (const float*)d_in[6];
    const float* b_convs = (const float*)d_in[7];

    float* out       = (float*)d_out;
    float* out_h     = out;
    float* out_cards = out + (size_t)N_NODES * HID;
    float* out_mh    = out_cards + (size_t)N_NODES * 2;
    float* out_hll   = out_mh + (size_t)N_NODES * NPERM;

    char* w = (char*)d_ws;
    int*   deg     = (int*)w;   w = align256(w + (size_t)N_NODES * 4);
    int*   offsets = (int*)w;   w = align256(w + (size_t)(N_NODES + 1) * 4);
    int*   cursor  = (int*)w;   w = align256(w + (size_t)N_NODES * 4);
    float* dis     = (float*)w; w = align256(w + (size_t)N_NODES * 4);
    int*   csr     = (int*)w;   w = align256(w + (size_t)(N_EDGES + N_NODES) * 4);
    uint*  mhp0    = (uint*)w;  w = align256(w + (size_t)N_NODES * 64 * 4);
    uint*  mhA     = (uint*)w;  w = align256(w + (size_t)N_NODES * 64 * 4);
    uint*  hp0     = (uint*)w;  w = align256(w + (size_t)N_NODES * 16 * 4);
    uint*  hllA    = (uint*)w;  w = align256(w + (size_t)N_NODES * 16 * 4);
    float* h_cur   = (float*)w; w = align256(w + (size_t)N_NODES * HID * 4);
    __hip_bfloat16* hWs = (__hip_bfloat16*)w;

    const int* src = ei;
    const int* dst = ei + N_EDGES;

    k_init_deg<<<(N_NODES + 255) / 256, 256, 0, stream>>>(deg);
    k_count_deg<<<(N_EDGES + 255) / 256, 256, 0, stream>>>(dst, deg);
    k_scan<<<1, 1024, 0, stream>>>(deg, offsets);
    k_dis_cursor<<<(N_NODES + 255) / 256, 256, 0, stream>>>(deg, offsets, dis, cursor, csr);
    k_fill<<<(N_EDGES + 255) / 256, 256, 0, stream>>>(src, dst, cursor, csr);

    k_pack_mh<<<(N_NODES * (NPERM / 2) + 255) / 256, 256, 0, stream>>>(mh0, mhp0);
    k_pack_hll<<<(N_NODES * (HLLM / 4) + 255) / 256, 256, 0, stream>>>(hll0, hp0);
    k_encoder<<<(N_NODES + 63) / 64, 256, 0, stream>>>(x, W_enc, b_enc, h_cur);

    // ---- hop 0 ----
    k_hll<<<(N_NODES + 15) / 16, 256, 0, stream>>>(offsets, csr, hp0, hllA, nullptr, out_cards, 0);
    k_mh<<<(N_NODES + 3) / 4, 256, 0, stream>>>(offsets, csr, mhp0, mhA, nullptr);
    k_convmm<<<(N_NODES + 63) / 64, 256, 0, stream>>>(h_cur, W_convs, dis, hWs);
    k_agg<<<(N_NODES + 3) / 4, 256, 0, stream>>>(offsets, csr, hWs, dis, b_convs, h_cur, h_cur);

    // ---- hop 1 ----
    k_hll<<<(N_NODES + 15) / 16, 256, 0, stream>>>(offsets, csr, hllA, nullptr, out_hll, out_cards, 1);
    k_mh<<<(N_NODES + 3) / 4, 256, 0, stream>>>(offsets, csr, mhA, nullptr, out_mh);
    k_convmm<<<(N_NODES + 63) / 64, 256, 0, stream>>>(h_cur, W_convs + HID * HID, dis, hWs + 0);
    k_agg<<<(N_NODES + 3) / 4, 256, 0, stream>>>(offsets, csr, hWs, dis, b_convs + HID, h_cur, out_h);
}

// Round 3
// 331.269 us; speedup vs baseline: 2.1265x; 1.2089x over previous
//
#include <hip/hip_runtime.h>
#include <hip/hip_bf16.h>
#include <climits>

typedef unsigned int uint;

#define N_NODES 50000
#define N_EDGES 800000
#define FDIM 128
#define HID 64
#define NPERM 128
#define HLLM 64
#define NB_SCAN 196  // ceil(50000/256)

// ---------------- degree / CSR build ----------------

__global__ void k_init_deg(int* deg) {
    int i = blockIdx.x * blockDim.x + threadIdx.x;
    if (i < N_NODES) deg[i] = 1;  // self loop
}

__global__ void k_count_deg(const int* __restrict__ dst, int* __restrict__ deg) {
    int e = blockIdx.x * blockDim.x + threadIdx.x;
    if (e < N_EDGES) atomicAdd(&deg[dst[e]], 1);
}

// phase 1: per-block (256 nodes) degree sums
__global__ void k_blocksum(const int* __restrict__ deg, int* __restrict__ bsum) {
    int i = blockIdx.x * 256 + threadIdx.x;
    int v = (i < N_NODES) ? deg[i] : 0;
#pragma unroll
    for (int off = 32; off >= 1; off >>= 1) v += __shfl_down(v, off);
    __shared__ int ws[4];
    if ((threadIdx.x & 63) == 0) ws[threadIdx.x >> 6] = v;
    __syncthreads();
    if (threadIdx.x == 0) bsum[blockIdx.x] = ws[0] + ws[1] + ws[2] + ws[3];
}

// phase 2: single-block exclusive scan of the NB_SCAN block sums
__global__ void k_scanb(const int* __restrict__ bsum, int* __restrict__ bpre) {
    __shared__ int s[256];
    int t = threadIdx.x;
    int v = (t < NB_SCAN) ? bsum[t] : 0;
    s[t] = v;
    __syncthreads();
    for (int off = 1; off < 256; off <<= 1) {
        int u = (t >= off) ? s[t - off] : 0;
        __syncthreads();
        s[t] += u;
        __syncthreads();
    }
    if (t < NB_SCAN) bpre[t] = s[t] - v;  // exclusive
}

// phase 3: per-block exclusive scan of degrees + block prefix -> offsets,
// plus dis / cursor / CSR self-loop (merged old k_dis_cursor)
__global__ void k_offsets(const int* __restrict__ deg, const int* __restrict__ bpre,
                          int* __restrict__ offsets, float* __restrict__ dis,
                          int* __restrict__ cursor, int* __restrict__ csr) {
    __shared__ int s[256];
    int t = threadIdx.x;
    int i = blockIdx.x * 256 + t;
    int v = (i < N_NODES) ? deg[i] : 0;
    s[t] = v;
    __syncthreads();
    for (int off = 1; off < 256; off <<= 1) {
        int u = (t >= off) ? s[t - off] : 0;
        __syncthreads();
        s[t] += u;
        __syncthreads();
    }
    if (i < N_NODES) {
        int o = bpre[blockIdx.x] + s[t] - v;
        offsets[i] = o;
        dis[i] = rsqrtf((float)v);
        csr[o] = i;          // self-loop first
        cursor[i] = o + 1;
        if (i == N_NODES - 1) offsets[N_NODES] = o + v;
    }
}

__global__ void k_fill(const int* __restrict__ src, const int* __restrict__ dst,
                       int* __restrict__ cursor, int* __restrict__ csr) {
    int e = blockIdx.x * blockDim.x + threadIdx.x;
    if (e < N_EDGES) {
        int p = atomicAdd(&cursor[dst[e]], 1);
        csr[p] = src[e];
    }
}

// ---------------- packing ----------------

// minhash int32 -> top 16 bits of float32 (monotone, error <= |v|/128)
__global__ void k_pack_mh(const int* __restrict__ mh, uint* __restrict__ mhp) {
    int i = blockIdx.x * 256 + threadIdx.x;
    if (i >= N_NODES * (NPERM / 2)) return;
    int2 v = ((const int2*)mh)[i];
    uint u0 = __float_as_uint((float)v.x) >> 16;
    uint u1 = __float_as_uint((float)v.y) >> 16;
    mhp[i] = u0 | (u1 << 16);
}

// hll int32 (<20, max-only so stays <256) -> u8
__global__ void k_pack_hll(const int* __restrict__ hll, uint* __restrict__ hp) {
    int i = blockIdx.x * 256 + threadIdx.x;
    if (i >= N_NODES * (HLLM / 4)) return;
    int4 v = ((const int4*)hll)[i];
    hp[i] = (uint)v.x | ((uint)v.y << 8) | ((uint)v.z << 16) | ((uint)v.w << 24);
}

// ---------------- dense GEMMs ----------------

__global__ void k_encoder(const float* __restrict__ x, const float* __restrict__ W,
                          const float* __restrict__ b, float* __restrict__ h) {
    __shared__ float Ws[FDIM * HID];  // 32 KB
    for (int idx = threadIdx.x; idx < FDIM * HID; idx += 256) Ws[idx] = W[idx];
    __syncthreads();
    int row = blockIdx.x * 64 + (threadIdx.x >> 2);
    int c0 = (threadIdx.x & 3) * 16;
    if (row >= N_NODES) return;
    float acc[16];
#pragma unroll
    for (int j = 0; j < 16; ++j) acc[j] = b[c0 + j];
    const float4* xr = (const float4*)(x + (size_t)row * FDIM);
    for (int k4 = 0; k4 < FDIM / 4; ++k4) {
        float4 xv = xr[k4];
        const float* wr = Ws + (k4 * 4) * HID + c0;
#pragma unroll
        for (int j = 0; j < 16; ++j) acc[j] = fmaf(xv.x, wr[j], acc[j]);
#pragma unroll
        for (int j = 0; j < 16; ++j) acc[j] = fmaf(xv.y, wr[HID + j], acc[j]);
#pragma unroll
        for (int j = 0; j < 16; ++j) acc[j] = fmaf(xv.z, wr[2 * HID + j], acc[j]);
#pragma unroll
        for (int j = 0; j < 16; ++j) acc[j] = fmaf(xv.w, wr[3 * HID + j], acc[j]);
    }
    float* hr = h + (size_t)row * HID + c0;
#pragma unroll
    for (int j = 0; j < 16; ++j) hr[j] = acc[j];
}

// hWs = bf16( dis ⊙ (h @ W_k) )
__global__ void k_convmm(const float* __restrict__ h, const float* __restrict__ W,
                         const float* __restrict__ dis, __hip_bfloat16* __restrict__ hWs) {
    __shared__ float Ws[HID * HID];  // 16 KB
    for (int idx = threadIdx.x; idx < HID * HID; idx += 256) Ws[idx] = W[idx];
    __syncthreads();
    int row = blockIdx.x * 64 + (threadIdx.x >> 2);
    int c0 = (threadIdx.x & 3) * 16;
    if (row >= N_NODES) return;
    float acc[16] = {0.f, 0.f, 0.f, 0.f, 0.f, 0.f, 0.f, 0.f,
                     0.f, 0.f, 0.f, 0.f, 0.f, 0.f, 0.f, 0.f};
    const float4* hr = (const float4*)(h + (size_t)row * HID);
    for (int k4 = 0; k4 < HID / 4; ++k4) {
        float4 hv = hr[k4];
        const float* wr = Ws + (k4 * 4) * HID + c0;
#pragma unroll
        for (int j = 0; j < 16; ++j) acc[j] = fmaf(hv.x, wr[j], acc[j]);
#pragma unroll
        for (int j = 0; j < 16; ++j) acc[j] = fmaf(hv.y, wr[HID + j], acc[j]);
#pragma unroll
        for (int j = 0; j < 16; ++j) acc[j] = fmaf(hv.z, wr[2 * HID + j], acc[j]);
#pragma unroll
        for (int j = 0; j < 16; ++j) acc[j] = fmaf(hv.w, wr[3 * HID + j], acc[j]);
    }
    float d = dis[row];
    __hip_bfloat16* o = hWs + (size_t)row * HID + c0;
#pragma unroll
    for (int j = 0; j < 16; ++j) o[j] = __float2bfloat16(d * acc[j]);
}

// ---------------- hash propagation (gather over CSR, unroll-4) ----------------

// HLL packed u8: 16 lanes per node (4 regs/lane), 16 nodes per 256-block.
__global__ void k_hll(const int* __restrict__ offsets, const int* __restrict__ csr,
                      const uint* __restrict__ hin, uint* __restrict__ hout_p,
                      float* __restrict__ hout_f, float* __restrict__ cards, int kcol) {
    int node = blockIdx.x * 16 + (threadIdx.x >> 4);
    int q = threadIdx.x & 15;
    if (node >= N_NODES) return;
    int s = offsets[node], e = offsets[node + 1];
    uint m0 = 0, m1 = 0, m2 = 0, m3 = 0;
#define HLL_ACC(vv) do { uint _v = (vv); \
        m0 = max(m0, _v & 0xFFu); m1 = max(m1, (_v >> 8) & 0xFFu); \
        m2 = max(m2, (_v >> 16) & 0xFFu); m3 = max(m3, _v >> 24); } while (0)
    int p = s;
    for (; p + 4 <= e; p += 4) {
        int j0 = csr[p], j1 = csr[p + 1], j2 = csr[p + 2], j3 = csr[p + 3];
        uint a = hin[(size_t)j0 * 16 + q];
        uint b = hin[(size_t)j1 * 16 + q];
        uint c = hin[(size_t)j2 * 16 + q];
        uint d = hin[(size_t)j3 * 16 + q];
        HLL_ACC(a); HLL_ACC(b); HLL_ACC(c); HLL_ACC(d);
    }
    for (; p < e; ++p) HLL_ACC(hin[(size_t)csr[p] * 16 + q]);
#undef HLL_ACC
    if (hout_p) hout_p[(size_t)node * 16 + q] = m0 | (m1 << 8) | (m2 << 16) | (m3 << 24);
    if (hout_f) {
        float4 w = {(float)m0, (float)m1, (float)m2, (float)m3};
        *(float4*)(hout_f + (size_t)node * HLLM + 4 * q) = w;
    }
    float v = exp2f(-(float)m0) + exp2f(-(float)m1) + exp2f(-(float)m2) + exp2f(-(float)m3);
    v += __shfl_xor(v, 1); v += __shfl_xor(v, 2);
    v += __shfl_xor(v, 4); v += __shfl_xor(v, 8);
    if (q == 0) {
        const float alphamm = (float)(0.7213 / (1.0 + 1.079 / 64.0) * 64.0 * 64.0);
        cards[(size_t)node * 2 + kcol] = alphamm / v;
    }
}

// minhash packed u16: one wave per node, lane = uint chunk (perms 2l, 2l+1).
__global__ void k_mh(const int* __restrict__ offsets, const int* __restrict__ csr,
                     const uint* __restrict__ mhin, uint* __restrict__ out_p,
                     float* __restrict__ out_f) {
    int node = blockIdx.x * 4 + (threadIdx.x >> 6);
    int l = threadIdx.x & 63;
    if (node >= N_NODES) return;
    int s = offsets[node], e = offsets[node + 1];
    uint mn0 = 0xFFFFu, mn1 = 0xFFFFu;
    int p = s;
    for (; p + 4 <= e; p += 4) {
        int j0 = csr[p], j1 = csr[p + 1], j2 = csr[p + 2], j3 = csr[p + 3];
        uint a = mhin[(size_t)j0 * 64 + l];
        uint b = mhin[(size_t)j1 * 64 + l];
        uint c = mhin[(size_t)j2 * 64 + l];
        uint d = mhin[(size_t)j3 * 64 + l];
        mn0 = min(mn0, a & 0xFFFFu); mn1 = min(mn1, a >> 16);
        mn0 = min(mn0, b & 0xFFFFu); mn1 = min(mn1, b >> 16);
        mn0 = min(mn0, c & 0xFFFFu); mn1 = min(mn1, c >> 16);
        mn0 = min(mn0, d & 0xFFFFu); mn1 = min(mn1, d >> 16);
    }
    for (; p < e; ++p) {
        uint a = mhin[(size_t)csr[p] * 64 + l];
        mn0 = min(mn0, a & 0xFFFFu); mn1 = min(mn1, a >> 16);
    }
    if (out_p) {
        out_p[(size_t)node * 64 + l] = mn0 | (mn1 << 16);
    } else {
        float2 w;
        w.x = __uint_as_float(mn0 << 16);
        w.y = __uint_as_float(mn1 << 16);
        *(float2*)(out_f + (size_t)node * NPERM + 2 * l) = w;
    }
}

// GCN aggregate over bf16 hWs rows (128 B = one cache line per row).
__global__ void k_agg(const int* __restrict__ offsets, const int* __restrict__ csr,
                      const __hip_bfloat16* __restrict__ hWs, const float* __restrict__ dis,
                      const float* __restrict__ b, const float* __restrict__ h_in,
                      float* __restrict__ h_out) {
    int node = blockIdx.x * 4 + (threadIdx.x >> 6);
    int c = threadIdx.x & 63;
    if (node >= N_NODES) return;
    int s = offsets[node], e = offsets[node + 1];
    float acc = 0.f;
    int p = s;
    for (; p + 4 <= e; p += 4) {
        int j0 = csr[p], j1 = csr[p + 1], j2 = csr[p + 2], j3 = csr[p + 3];
        float a = __bfloat162float(hWs[(size_t)j0 * HID + c]);
        float bb = __bfloat162float(hWs[(size_t)j1 * HID + c]);
        float cc = __bfloat162float(hWs[(size_t)j2 * HID + c]);
        float dd = __bfloat162float(hWs[(size_t)j3 * HID + c]);
        acc += a + bb + cc + dd;
    }
    for (; p < e; ++p) acc += __bfloat162float(hWs[(size_t)csr[p] * HID + c]);
    h_out[(size_t)node * HID + c] = h_in[(size_t)node * HID + c] + b[c] + dis[node] * acc;
}

// ---------------- driver ----------------

static inline char* align256(char* p) {
    return (char*)(((uintptr_t)p + 255) & ~(uintptr_t)255);
}

extern "C" void kernel_launch(void* const* d_in, const int* in_sizes, int n_in,
                              void* d_out, int out_size, void* d_ws, size_t ws_size,
                              hipStream_t stream) {
    const float* x       = (const float*)d_in[0];
    const int*   ei      = (const int*)d_in[1];
    const int*   mh0     = (const int*)d_in[2];
    const int*   hll0    = (const int*)d_in[3];
    const float* W_enc   = (const float*)d_in[4];
    const float* b_enc   = (const float*)d_in[5];
    const float* W_convs = (const float*)d_in[6];
    const float* b_convs = (const float*)d_in[7];

    float* out       = (float*)d_out;
    float* out_h     = out;
    float* out_cards = out + (size_t)N_NODES * HID;
    float* out_mh    = out_cards + (size_t)N_NODES * 2;
    float* out_hll   = out_mh + (size_t)N_NODES * NPERM;

    char* w = (char*)d_ws;
    int*   deg     = (int*)w;   w = align256(w + (size_t)N_NODES * 4);
    int*   offsets = (int*)w;   w = align256(w + (size_t)(N_NODES + 1) * 4);
    int*   cursor  = (int*)w;   w = align256(w + (size_t)N_NODES * 4);
    float* dis     = (float*)w; w = align256(w + (size_t)N_NODES * 4);
    int*   bsum    = (int*)w;   w = align256(w + (size_t)NB_SCAN * 4);
    int*   bpre    = (int*)w;   w = align256(w + (size_t)NB_SCAN * 4);
    int*   csr     = (int*)w;   w = align256(w + (size_t)(N_EDGES + N_NODES) * 4);
    uint*  mhp0    = (uint*)w;  w = align256(w + (size_t)N_NODES * 64 * 4);
    uint*  mhA     = (uint*)w;  w = align256(w + (size_t)N_NODES * 64 * 4);
    uint*  hp0     = (uint*)w;  w = align256(w + (size_t)N_NODES * 16 * 4);
    uint*  hllA    = (uint*)w;  w = align256(w + (size_t)N_NODES * 16 * 4);
    float* h_cur   = (float*)w; w = align256(w + (size_t)N_NODES * HID * 4);
    __hip_bfloat16* hWs = (__hip_bfloat16*)w;

    const int* src = ei;
    const int* dst = ei + N_EDGES;

    k_init_deg<<<(N_NODES + 255) / 256, 256, 0, stream>>>(deg);
    k_count_deg<<<(N_EDGES + 255) / 256, 256, 0, stream>>>(dst, deg);
    k_blocksum<<<NB_SCAN, 256, 0, stream>>>(deg, bsum);
    k_scanb<<<1, 256, 0, stream>>>(bsum, bpre);
    k_offsets<<<NB_SCAN, 256, 0, stream>>>(deg, bpre, offsets, dis, cursor, csr);
    k_fill<<<(N_EDGES + 255) / 256, 256, 0, stream>>>(src, dst, cursor, csr);

    k_pack_mh<<<(N_NODES * (NPERM / 2) + 255) / 256, 256, 0, stream>>>(mh0, mhp0);
    k_pack_hll<<<(N_NODES * (HLLM / 4) + 255) / 256, 256, 0, stream>>>(hll0, hp0);
    k_encoder<<<(N_NODES + 63) / 64, 256, 0, stream>>>(x, W_enc, b_enc, h_cur);

    // ---- hop 0 ----
    k_hll<<<(N_NODES + 15) / 16, 256, 0, stream>>>(offsets, csr, hp0, hllA, nullptr, out_cards, 0);
    k_mh<<<(N_NODES + 3) / 4, 256, 0, stream>>>(offsets, csr, mhp0, mhA, nullptr);
    k_convmm<<<(N_NODES + 63) / 64, 256, 0, stream>>>(h_cur, W_convs, dis, hWs);
    k_agg<<<(N_NODES + 3) / 4, 256, 0, stream>>>(offsets, csr, hWs, dis, b_convs, h_cur, h_cur);

    // ---- hop 1 ----
    k_hll<<<(N_NODES + 15) / 16, 256, 0, stream>>>(offsets, csr, hllA, nullptr, out_hll, out_cards, 1);
    k_mh<<<(N_NODES + 3) / 4, 256, 0, stream>>>(offsets, csr, mhA, nullptr, out_mh);
    k_convmm<<<(N_NODES + 63) / 64, 256, 0, stream>>>(h_cur, W_convs + HID * HID, dis, hWs);
    k_agg<<<(N_NODES + 3) / 4, 256, 0, stream>>>(offsets, csr, hWs, dis, b_convs + HID, h_cur, out_h);
}

// Round 4
// 311.980 us; speedup vs baseline: 2.2580x; 1.0618x over previous
//
#include <hip/hip_runtime.h>
#include <hip/hip_bf16.h>
#include <climits>

typedef unsigned int uint;

#define N_NODES 50000
#define N_EDGES 800000
#define FDIM 128
#define HID 64
#define NPERM 128
#define HLLM 64

#define BSHIFT 9
#define BNODES 512                 // nodes per bucket
#define NBUCK 98                   // ceil(50000/512)
#define FILL_BLOCKS 256
#define FILL_ROUNDS 13             // ceil(800000/(256*256))
#define CAP 64                     // staging entries per bucket
#define HIST_BLOCKS 390
#define MH_BLOCKS 12500            // 50000*64/256
#define HLL_BLOCKS 3125            // 50000*16/256
#define SLICE_CAP 12288

// ---------------- prep: pack hashes + coarse dst histogram ----------------

__global__ void k_prep(const int* __restrict__ mh, uint* __restrict__ mhp,
                       const int* __restrict__ hll, uint* __restrict__ hp,
                       const int* __restrict__ dst, int* __restrict__ bktcnt) {
    int b = blockIdx.x;
    if (b < MH_BLOCKS) {
        // minhash int32 -> top 16 bits of float32 (monotone, err <= |v|/128)
        int i = b * 256 + threadIdx.x;
        int2 v = ((const int2*)mh)[i];
        uint u0 = __float_as_uint((float)v.x) >> 16;
        uint u1 = __float_as_uint((float)v.y) >> 16;
        mhp[i] = u0 | (u1 << 16);
    } else if (b < MH_BLOCKS + HLL_BLOCKS) {
        // hll int32 (<20; max-only keeps it <256) -> u8
        int i = (b - MH_BLOCKS) * 256 + threadIdx.x;
        int4 v = ((const int4*)hll)[i];
        hp[i] = (uint)v.x | ((uint)v.y << 8) | ((uint)v.z << 16) | ((uint)v.w << 24);
    } else {
        __shared__ int h[NBUCK];
        for (int i = threadIdx.x; i < NBUCK; i += 256) h[i] = 0;
        __syncthreads();
        for (int e = (b - MH_BLOCKS - HLL_BLOCKS) * 256 + threadIdx.x; e < N_EDGES;
             e += HIST_BLOCKS * 256)
            atomicAdd(&h[dst[e] >> BSHIFT], 1);
        __syncthreads();
        for (int i = threadIdx.x; i < NBUCK; i += 256)
            if (h[i]) atomicAdd(&bktcnt[i], h[i]);
    }
}

// exclusive scan of bucket counts -> gbase/gcur; also offsets[N] constant
__global__ void k_bktscan(const int* __restrict__ bktcnt, int* __restrict__ gbase,
                          int* __restrict__ gcur, int* __restrict__ offsets) {
    __shared__ int s[128];
    int t = threadIdx.x;
    int v = (t < NBUCK) ? bktcnt[t] : 0;
    s[t] = v;
    __syncthreads();
    for (int off = 1; off < 128; off <<= 1) {
        int u = (t >= off) ? s[t - off] : 0;
        __syncthreads();
        s[t] += u;
        __syncthreads();
    }
    if (t < NBUCK) { int ex = s[t] - v; gbase[t] = ex; gcur[t] = ex; }
    if (t == 0) offsets[N_NODES] = N_EDGES + N_NODES;
}

// ---------------- pass A: bucketize edges with LDS staging ----------------

__global__ void k_bucket(const int* __restrict__ src, const int* __restrict__ dst,
                         int* __restrict__ gcur, uint* __restrict__ ebuf) {
    __shared__ uint buf[NBUCK][CAP];
    __shared__ int lcnt[NBUCK];
    for (int i = threadIdx.x; i < NBUCK; i += 256) lcnt[i] = 0;
    __syncthreads();
    for (int r = 0; r < FILL_ROUNDS; ++r) {
        int e = (r * FILL_BLOCKS + (int)blockIdx.x) * 256 + (int)threadIdx.x;
        if (e < N_EDGES) {
            int d = dst[e];
            uint en = ((uint)src[e] << BSHIFT) | (uint)(d & (BNODES - 1));
            int bb = d >> BSHIFT;
            int pos = atomicAdd(&lcnt[bb], 1);
            if (pos < CAP) buf[bb][pos] = en;
            else { int gp = atomicAdd(&gcur[bb], 1); ebuf[gp] = en; }  // ~never
        }
        __syncthreads();
        for (int bb = threadIdx.x; bb < NBUCK; bb += 256) {
            int c = min(lcnt[bb], CAP);
            while (c >= 16) {
                int gp = atomicAdd(&gcur[bb], 16);
                for (int i = 0; i < 16; ++i) ebuf[gp + i] = buf[bb][c - 16 + i];
                c -= 16;
            }
            lcnt[bb] = c;
        }
        __syncthreads();
    }
    for (int bb = threadIdx.x; bb < NBUCK; bb += 256) {
        int c = min(lcnt[bb], CAP);
        if (c > 0) {
            int gp = atomicAdd(&gcur[bb], c);
            for (int i = 0; i < c; ++i) ebuf[gp + i] = buf[bb][i];
        }
    }
}

// ---------------- pass B: build CSR slice in LDS; emit offsets/dis ----------------

__global__ void __launch_bounds__(256) k_csr(const uint* __restrict__ ebuf,
                      const int* __restrict__ gbase, const int* __restrict__ bktcnt,
                      int* __restrict__ offsets, float* __restrict__ dis,
                      int* __restrict__ csr) {
    __shared__ int lcur[BNODES];
    __shared__ int tsum[256];
    __shared__ uint slice[SLICE_CAP];
    int b = blockIdx.x;
    int lo = b << BSHIFT;
    int nbkt = min(BNODES, N_NODES - lo);
    int ebase = gbase[b];
    int ecnt = bktcnt[b];
    int t = threadIdx.x;
    lcur[t] = 0; lcur[t + 256] = 0;
    __syncthreads();
    // pass 1: per-node histogram
    for (int i = t; i < ecnt; i += 256)
        atomicAdd(&lcur[ebuf[ebase + i] & (BNODES - 1)], 1);
    __syncthreads();
    // scan (thread owns nodes 2t, 2t+1)
    int a0 = lcur[2 * t], a1 = lcur[2 * t + 1];
    tsum[t] = a0 + a1;
    __syncthreads();
    for (int off = 1; off < 256; off <<= 1) {
        int u = (t >= off) ? tsum[t - off] : 0;
        __syncthreads();
        tsum[t] += u;
        __syncthreads();
    }
    int pre = tsum[t] - (a0 + a1);
    {
        int dl = 2 * t;
        if (dl < nbkt) {
            int st = pre + dl;
            slice[st] = (uint)(lo + dl);       // self-loop first
            lcur[dl] = st + 1;
            offsets[lo + dl] = ebase + lo + st;
            dis[lo + dl] = rsqrtf((float)(a0 + 1));
        }
        dl = 2 * t + 1;
        if (dl < nbkt) {
            int st = pre + a0 + dl;
            slice[st] = (uint)(lo + dl);
            lcur[dl] = st + 1;
            offsets[lo + dl] = ebase + lo + st;
            dis[lo + dl] = rsqrtf((float)(a1 + 1));
        }
    }
    __syncthreads();
    // pass 2: place edges
    for (int i = t; i < ecnt; i += 256) {
        uint en = ebuf[ebase + i];
        int dl = en & (BNODES - 1);
        int p = atomicAdd(&lcur[dl], 1);
        slice[p] = en >> BSHIFT;
    }
    __syncthreads();
    int slen = ecnt + nbkt;
    int gb = ebase + lo;
    for (int i = t; i < slen; i += 256) csr[gb + i] = (int)slice[i];
}

// ---------------- dense GEMMs ----------------

__global__ void k_encoder(const float* __restrict__ x, const float* __restrict__ W,
                          const float* __restrict__ b, float* __restrict__ h) {
    __shared__ float Ws[FDIM * HID];
    for (int idx = threadIdx.x; idx < FDIM * HID; idx += 256) Ws[idx] = W[idx];
    __syncthreads();
    int row = blockIdx.x * 64 + (threadIdx.x >> 2);
    int c0 = (threadIdx.x & 3) * 16;
    if (row >= N_NODES) return;
    float acc[16];
#pragma unroll
    for (int j = 0; j < 16; ++j) acc[j] = b[c0 + j];
    const float4* xr = (const float4*)(x + (size_t)row * FDIM);
    for (int k4 = 0; k4 < FDIM / 4; ++k4) {
        float4 xv = xr[k4];
        const float* wr = Ws + (k4 * 4) * HID + c0;
#pragma unroll
        for (int j = 0; j < 16; ++j) acc[j] = fmaf(xv.x, wr[j], acc[j]);
#pragma unroll
        for (int j = 0; j < 16; ++j) acc[j] = fmaf(xv.y, wr[HID + j], acc[j]);
#pragma unroll
        for (int j = 0; j < 16; ++j) acc[j] = fmaf(xv.z, wr[2 * HID + j], acc[j]);
#pragma unroll
        for (int j = 0; j < 16; ++j) acc[j] = fmaf(xv.w, wr[3 * HID + j], acc[j]);
    }
    float* hr = h + (size_t)row * HID + c0;
#pragma unroll
    for (int j = 0; j < 16; ++j) hr[j] = acc[j];
}

__global__ void k_convmm(const float* __restrict__ h, const float* __restrict__ W,
                         const float* __restrict__ dis, __hip_bfloat16* __restrict__ hWs) {
    __shared__ float Ws[HID * HID];
    for (int idx = threadIdx.x; idx < HID * HID; idx += 256) Ws[idx] = W[idx];
    __syncthreads();
    int row = blockIdx.x * 64 + (threadIdx.x >> 2);
    int c0 = (threadIdx.x & 3) * 16;
    if (row >= N_NODES) return;
    float acc[16] = {0.f, 0.f, 0.f, 0.f, 0.f, 0.f, 0.f, 0.f,
                     0.f, 0.f, 0.f, 0.f, 0.f, 0.f, 0.f, 0.f};
    const float4* hr = (const float4*)(h + (size_t)row * HID);
    for (int k4 = 0; k4 < HID / 4; ++k4) {
        float4 hv = hr[k4];
        const float* wr = Ws + (k4 * 4) * HID + c0;
#pragma unroll
        for (int j = 0; j < 16; ++j) acc[j] = fmaf(hv.x, wr[j], acc[j]);
#pragma unroll
        for (int j = 0; j < 16; ++j) acc[j] = fmaf(hv.y, wr[HID + j], acc[j]);
#pragma unroll
        for (int j = 0; j < 16; ++j) acc[j] = fmaf(hv.z, wr[2 * HID + j], acc[j]);
#pragma unroll
        for (int j = 0; j < 16; ++j) acc[j] = fmaf(hv.w, wr[3 * HID + j], acc[j]);
    }
    float d = dis[row];
    __hip_bfloat16* o = hWs + (size_t)row * HID + c0;
#pragma unroll
    for (int j = 0; j < 16; ++j) o[j] = __float2bfloat16(d * acc[j]);
}

// ---------------- hash propagation (gather over CSR, unroll-8) ----------------

__global__ void k_hll(const int* __restrict__ offsets, const int* __restrict__ csr,
                      const uint* __restrict__ hin, uint* __restrict__ hout_p,
                      float* __restrict__ hout_f, float* __restrict__ cards, int kcol) {
    int node = blockIdx.x * 16 + (threadIdx.x >> 4);
    int q = threadIdx.x & 15;
    if (node >= N_NODES) return;
    int s = offsets[node], e = offsets[node + 1];
    uint m0 = 0, m1 = 0, m2 = 0, m3 = 0;
#define HLL_ACC(vv) do { uint _v = (vv); \
        m0 = max(m0, _v & 0xFFu); m1 = max(m1, (_v >> 8) & 0xFFu); \
        m2 = max(m2, (_v >> 16) & 0xFFu); m3 = max(m3, _v >> 24); } while (0)
    int p = s;
    for (; p + 8 <= e; p += 8) {
        int j0 = csr[p], j1 = csr[p + 1], j2 = csr[p + 2], j3 = csr[p + 3];
        int j4 = csr[p + 4], j5 = csr[p + 5], j6 = csr[p + 6], j7 = csr[p + 7];
        uint a0 = hin[(size_t)j0 * 16 + q];
        uint a1 = hin[(size_t)j1 * 16 + q];
        uint a2 = hin[(size_t)j2 * 16 + q];
        uint a3 = hin[(size_t)j3 * 16 + q];
        uint a4 = hin[(size_t)j4 * 16 + q];
        uint a5 = hin[(size_t)j5 * 16 + q];
        uint a6 = hin[(size_t)j6 * 16 + q];
        uint a7 = hin[(size_t)j7 * 16 + q];
        HLL_ACC(a0); HLL_ACC(a1); HLL_ACC(a2); HLL_ACC(a3);
        HLL_ACC(a4); HLL_ACC(a5); HLL_ACC(a6); HLL_ACC(a7);
    }
    for (; p < e; ++p) HLL_ACC(hin[(size_t)csr[p] * 16 + q]);
#undef HLL_ACC
    if (hout_p) hout_p[(size_t)node * 16 + q] = m0 | (m1 << 8) | (m2 << 16) | (m3 << 24);
    if (hout_f) {
        float4 w = {(float)m0, (float)m1, (float)m2, (float)m3};
        *(float4*)(hout_f + (size_t)node * HLLM + 4 * q) = w;
    }
    float v = exp2f(-(float)m0) + exp2f(-(float)m1) + exp2f(-(float)m2) + exp2f(-(float)m3);
    v += __shfl_xor(v, 1); v += __shfl_xor(v, 2);
    v += __shfl_xor(v, 4); v += __shfl_xor(v, 8);
    if (q == 0) {
        const float alphamm = (float)(0.7213 / (1.0 + 1.079 / 64.0) * 64.0 * 64.0);
        cards[(size_t)node * 2 + kcol] = alphamm / v;
    }
}

__global__ void k_mh(const int* __restrict__ offsets, const int* __restrict__ csr,
                     const uint* __restrict__ mhin, uint* __restrict__ out_p,
                     float* __restrict__ out_f) {
    int node = blockIdx.x * 4 + (threadIdx.x >> 6);
    int l = threadIdx.x & 63;
    if (node >= N_NODES) return;
    int s = offsets[node], e = offsets[node + 1];
    uint mn0 = 0xFFFFu, mn1 = 0xFFFFu, mn2 = 0xFFFFu, mn3 = 0xFFFFu;
    int p = s;
    for (; p + 8 <= e; p += 8) {
        int j0 = csr[p], j1 = csr[p + 1], j2 = csr[p + 2], j3 = csr[p + 3];
        int j4 = csr[p + 4], j5 = csr[p + 5], j6 = csr[p + 6], j7 = csr[p + 7];
        uint a0 = mhin[(size_t)j0 * 64 + l];
        uint a1 = mhin[(size_t)j1 * 64 + l];
        uint a2 = mhin[(size_t)j2 * 64 + l];
        uint a3 = mhin[(size_t)j3 * 64 + l];
        uint a4 = mhin[(size_t)j4 * 64 + l];
        uint a5 = mhin[(size_t)j5 * 64 + l];
        uint a6 = mhin[(size_t)j6 * 64 + l];
        uint a7 = mhin[(size_t)j7 * 64 + l];
        mn0 = min(mn0, min(a0 & 0xFFFFu, a1 & 0xFFFFu));
        mn1 = min(mn1, min(a0 >> 16, a1 >> 16));
        mn2 = min(mn2, min(a2 & 0xFFFFu, a3 & 0xFFFFu));
        mn3 = min(mn3, min(a2 >> 16, a3 >> 16));
        mn0 = min(mn0, min(a4 & 0xFFFFu, a5 & 0xFFFFu));
        mn1 = min(mn1, min(a4 >> 16, a5 >> 16));
        mn2 = min(mn2, min(a6 & 0xFFFFu, a7 & 0xFFFFu));
        mn3 = min(mn3, min(a6 >> 16, a7 >> 16));
    }
    for (; p < e; ++p) {
        uint a = mhin[(size_t)csr[p] * 64 + l];
        mn0 = min(mn0, a & 0xFFFFu); mn1 = min(mn1, a >> 16);
    }
    mn0 = min(mn0, mn2); mn1 = min(mn1, mn3);
    if (out_p) {
        out_p[(size_t)node * 64 + l] = mn0 | (mn1 << 16);
    } else {
        float2 w;
        w.x = __uint_as_float(mn0 << 16);
        w.y = __uint_as_float(mn1 << 16);
        *(float2*)(out_f + (size_t)node * NPERM + 2 * l) = w;
    }
}

__global__ void k_agg(const int* __restrict__ offsets, const int* __restrict__ csr,
                      const __hip_bfloat16* __restrict__ hWs, const float* __restrict__ dis,
                      const float* __restrict__ b, const float* __restrict__ h_in,
                      float* __restrict__ h_out) {
    int node = blockIdx.x * 4 + (threadIdx.x >> 6);
    int c = threadIdx.x & 63;
    if (node >= N_NODES) return;
    int s = offsets[node], e = offsets[node + 1];
    const unsigned short* hw = (const unsigned short*)hWs;
    float acc0 = 0.f, acc1 = 0.f;
    int p = s;
    for (; p + 8 <= e; p += 8) {
        int j0 = csr[p], j1 = csr[p + 1], j2 = csr[p + 2], j3 = csr[p + 3];
        int j4 = csr[p + 4], j5 = csr[p + 5], j6 = csr[p + 6], j7 = csr[p + 7];
        uint a0 = hw[(size_t)j0 * HID + c];
        uint a1 = hw[(size_t)j1 * HID + c];
        uint a2 = hw[(size_t)j2 * HID + c];
        uint a3 = hw[(size_t)j3 * HID + c];
        uint a4 = hw[(size_t)j4 * HID + c];
        uint a5 = hw[(size_t)j5 * HID + c];
        uint a6 = hw[(size_t)j6 * HID + c];
        uint a7 = hw[(size_t)j7 * HID + c];
        acc0 += __uint_as_float(a0 << 16) + __uint_as_float(a1 << 16)
              + __uint_as_float(a2 << 16) + __uint_as_float(a3 << 16);
        acc1 += __uint_as_float(a4 << 16) + __uint_as_float(a5 << 16)
              + __uint_as_float(a6 << 16) + __uint_as_float(a7 << 16);
    }
    for (; p < e; ++p)
        acc0 += __uint_as_float((uint)hw[(size_t)csr[p] * HID + c] << 16);
    float acc = acc0 + acc1;
    h_out[(size_t)node * HID + c] = h_in[(size_t)node * HID + c] + b[c] + dis[node] * acc;
}

// ---------------- driver ----------------

static inline char* align256(char* p) {
    return (char*)(((uintptr_t)p + 255) & ~(uintptr_t)255);
}

extern "C" void kernel_launch(void* const* d_in, const int* in_sizes, int n_in,
                              void* d_out, int out_size, void* d_ws, size_t ws_size,
                              hipStream_t stream) {
    const float* x       = (const float*)d_in[0];
    const int*   ei      = (const int*)d_in[1];
    const int*   mh0     = (const int*)d_in[2];
    const int*   hll0    = (const int*)d_in[3];
    const float* W_enc   = (const float*)d_in[4];
    const float* b_enc   = (const float*)d_in[5];
    const float* W_convs = (const float*)d_in[6];
    const float* b_convs = (const float*)d_in[7];

    float* out       = (float*)d_out;
    float* out_h     = out;
    float* out_cards = out + (size_t)N_NODES * HID;
    float* out_mh    = out_cards + (size_t)N_NODES * 2;
    float* out_hll   = out_mh + (size_t)N_NODES * NPERM;

    char* w = (char*)d_ws;
    int*   bktcnt  = (int*)w;   w = align256(w + (size_t)NBUCK * 4);
    int*   gbase   = (int*)w;   w = align256(w + (size_t)NBUCK * 4);
    int*   gcur    = (int*)w;   w = align256(w + (size_t)NBUCK * 4);
    int*   offsets = (int*)w;   w = align256(w + (size_t)(N_NODES + 1) * 4);
    float* dis     = (float*)w; w = align256(w + (size_t)N_NODES * 4);
    int*   csr     = (int*)w;   w = align256(w + (size_t)(N_EDGES + N_NODES) * 4);
    uint*  mhp0    = (uint*)w;  w = align256(w + (size_t)N_NODES * 64 * 4);
    uint*  mhA     = (uint*)w;  w = align256(w + (size_t)N_NODES * 64 * 4);
    uint*  hp0     = (uint*)w;  w = align256(w + (size_t)N_NODES * 16 * 4);
    uint*  hllA    = (uint*)w;  w = align256(w + (size_t)N_NODES * 16 * 4);
    float* h_cur   = (float*)w; w = align256(w + (size_t)N_NODES * HID * 4);
    __hip_bfloat16* hWs = (__hip_bfloat16*)w;
    uint*  ebuf    = mhA;  // build-phase only; mhA first written after k_csr consumed ebuf

    const int* src = ei;
    const int* dst = ei + N_EDGES;

    hipMemsetAsync(bktcnt, 0, (size_t)NBUCK * 4, stream);
    k_prep<<<MH_BLOCKS + HLL_BLOCKS + HIST_BLOCKS, 256, 0, stream>>>(mh0, mhp0, hll0, hp0, dst, bktcnt);
    k_bktscan<<<1, 128, 0, stream>>>(bktcnt, gbase, gcur, offsets);
    k_bucket<<<FILL_BLOCKS, 256, 0, stream>>>(src, dst, gcur, ebuf);
    k_csr<<<NBUCK, 256, 0, stream>>>(ebuf, gbase, bktcnt, offsets, dis, csr);
    k_encoder<<<(N_NODES + 63) / 64, 256, 0, stream>>>(x, W_enc, b_enc, h_cur);

    // ---- hop 0 ----
    k_hll<<<(N_NODES + 15) / 16, 256, 0, stream>>>(offsets, csr, hp0, hllA, nullptr, out_cards, 0);
    k_mh<<<(N_NODES + 3) / 4, 256, 0, stream>>>(offsets, csr, mhp0, mhA, nullptr);
    k_convmm<<<(N_NODES + 63) / 64, 256, 0, stream>>>(h_cur, W_convs, dis, hWs);
    k_agg<<<(N_NODES + 3) / 4, 256, 0, stream>>>(offsets, csr, hWs, dis, b_convs, h_cur, h_cur);

    // ---- hop 1 ----
    k_hll<<<(N_NODES + 15) / 16, 256, 0, stream>>>(offsets, csr, hllA, nullptr, out_hll, out_cards, 1);
    k_mh<<<(N_NODES + 3) / 4, 256, 0, stream>>>(offsets, csr, mhA, nullptr, out_mh);
    k_convmm<<<(N_NODES + 63) / 64, 256, 0, stream>>>(h_cur, W_convs + HID * HID, dis, hWs);
    k_agg<<<(N_NODES + 3) / 4, 256, 0, stream>>>(offsets, csr, hWs, dis, b_convs + HID, h_cur, out_h);
}

// Round 5
// 265.045 us; speedup vs baseline: 2.6578x; 1.1771x over previous
//
#include <hip/hip_runtime.h>
#include <hip/hip_bf16.h>
#include <climits>

typedef unsigned int uint;

#define N_NODES 50000
#define N_EDGES 800000
#define FDIM 128
#define HID 64
#define NPERM 128
#define HLLM 64

#define BSHIFT 8
#define BNODES 256                 // nodes per bucket
#define NBUCK 196                  // ceil(50000/256)
#define SCAT_BLOCKS 256
#define EDGES_PER_BLK 3125         // 800000/256 exactly
#define HIST_BLOCKS 390
#define MH_BLOCKS 12500            // 50000*64/256
#define HLL_BLOCKS 3125            // 50000*16/256
#define SLICE_CAP 6400

// ---------------- prep: pack hashes + coarse dst histogram ----------------

__global__ void k_prep(const int* __restrict__ mh, uint* __restrict__ mhp,
                       const int* __restrict__ hll, uint* __restrict__ hp,
                       const int* __restrict__ dst, int* __restrict__ bktcnt) {
    int b = blockIdx.x;
    if (b < MH_BLOCKS) {
        // minhash int32 -> top 16 bits of float32 (monotone, err <= |v|/128)
        int i = b * 256 + threadIdx.x;
        int2 v = ((const int2*)mh)[i];
        uint u0 = __float_as_uint((float)v.x) >> 16;
        uint u1 = __float_as_uint((float)v.y) >> 16;
        mhp[i] = u0 | (u1 << 16);
    } else if (b < MH_BLOCKS + HLL_BLOCKS) {
        // hll int32 (<20; max-only keeps it <256) -> u8
        int i = (b - MH_BLOCKS) * 256 + threadIdx.x;
        int4 v = ((const int4*)hll)[i];
        hp[i] = (uint)v.x | ((uint)v.y << 8) | ((uint)v.z << 16) | ((uint)v.w << 24);
    } else {
        __shared__ int h[NBUCK];
        for (int i = threadIdx.x; i < NBUCK; i += 256) h[i] = 0;
        __syncthreads();
        for (int e = (b - MH_BLOCKS - HLL_BLOCKS) * 256 + threadIdx.x; e < N_EDGES;
             e += HIST_BLOCKS * 256)
            atomicAdd(&h[dst[e] >> BSHIFT], 1);
        __syncthreads();
        for (int i = threadIdx.x; i < NBUCK; i += 256)
            if (h[i]) atomicAdd(&bktcnt[i], h[i]);
    }
}

// exclusive scan of bucket counts -> gbase/gcur; also offsets[N] constant
__global__ void k_bktscan(const int* __restrict__ bktcnt, int* __restrict__ gbase,
                          int* __restrict__ gcur, int* __restrict__ offsets) {
    __shared__ int s[256];
    int t = threadIdx.x;
    int v = (t < NBUCK) ? bktcnt[t] : 0;
    s[t] = v;
    __syncthreads();
    for (int off = 1; off < 256; off <<= 1) {
        int u = (t >= off) ? s[t - off] : 0;
        __syncthreads();
        s[t] += u;
        __syncthreads();
    }
    if (t < NBUCK) { int ex = s[t] - v; gbase[t] = ex; gcur[t] = ex; }
    if (t == 0) offsets[N_NODES] = N_EDGES + N_NODES;
}

// ---------------- pass A: block-local multisplit scatter ----------------

__global__ void __launch_bounds__(256) k_scatter(const int* __restrict__ src,
                          const int* __restrict__ dst,
                          int* __restrict__ gcur, uint* __restrict__ ebuf) {
    __shared__ uint ecache[EDGES_PER_BLK];
    __shared__ int cnt[NBUCK];
    __shared__ int cur[NBUCK];
    int t = threadIdx.x;
    for (int i = t; i < NBUCK; i += 256) cnt[i] = 0;
    __syncthreads();
    int e0 = blockIdx.x * EDGES_PER_BLK;
    for (int i = t; i < EDGES_PER_BLK; i += 256) {
        int d = dst[e0 + i];
        int s = src[e0 + i];
        ecache[i] = ((uint)s << 16) | (uint)d;   // both < 65536
        atomicAdd(&cnt[d >> BSHIFT], 1);
    }
    __syncthreads();
    // one contiguous range per bucket for this block
    for (int b = t; b < NBUCK; b += 256)
        cur[b] = atomicAdd(&gcur[b], cnt[b]);
    __syncthreads();
    for (int i = t; i < EDGES_PER_BLK; i += 256) {
        uint en = ecache[i];
        uint d = en & 0xFFFFu;
        int p = atomicAdd(&cur[d >> BSHIFT], 1);
        ebuf[p] = ((en >> 16) << BSHIFT) | (d & (BNODES - 1));
    }
}

// ---------------- pass B: build CSR slice in LDS; emit offsets/dis ----------------

__global__ void __launch_bounds__(256) k_csr(const uint* __restrict__ ebuf,
                      const int* __restrict__ gbase, const int* __restrict__ bktcnt,
                      int* __restrict__ offsets, float* __restrict__ dis,
                      int* __restrict__ csr) {
    __shared__ int lcur[BNODES];
    __shared__ int ssum[256];
    __shared__ uint slice[SLICE_CAP];
    int b = blockIdx.x;
    int lo = b << BSHIFT;
    int nbkt = min(BNODES, N_NODES - lo);
    int ebase = gbase[b];
    int ecnt = bktcnt[b];
    int t = threadIdx.x;
    lcur[t] = 0;
    __syncthreads();
    // pass 1: per-node in-degree histogram
    for (int i = t; i < ecnt; i += 256)
        atomicAdd(&lcur[ebuf[ebase + i] & (BNODES - 1)], 1);
    __syncthreads();
    int a0 = lcur[t];        // in-degree of node lo+t (0 if t>=nbkt)
    ssum[t] = a0;
    __syncthreads();
    for (int off = 1; off < 256; off <<= 1) {
        int u = (t >= off) ? ssum[t - off] : 0;
        __syncthreads();
        ssum[t] += u;
        __syncthreads();
    }
    int pre = ssum[t] - a0;  // exclusive prefix of degrees within bucket
    if (t < nbkt) {
        int st = pre + t;    // slice position including preceding self-loops
        slice[st] = (uint)(lo + t);       // self-loop first
        lcur[t] = st + 1;
        offsets[lo + t] = ebase + lo + st;
        dis[lo + t] = rsqrtf((float)(a0 + 1));
    }
    __syncthreads();
    // pass 2: place edges
    for (int i = t; i < ecnt; i += 256) {
        uint en = ebuf[ebase + i];
        int p = atomicAdd(&lcur[en & (BNODES - 1)], 1);
        slice[p] = en >> BSHIFT;
    }
    __syncthreads();
    int slen = ecnt + nbkt;
    int gb = ebase + lo;
    for (int i = t; i < slen; i += 256) csr[gb + i] = (int)slice[i];
}

// ---------------- dense GEMMs ----------------

__global__ void k_encoder(const float* __restrict__ x, const float* __restrict__ W,
                          const float* __restrict__ b, float* __restrict__ h) {
    __shared__ float Ws[FDIM * HID];
    for (int idx = threadIdx.x; idx < FDIM * HID; idx += 256) Ws[idx] = W[idx];
    __syncthreads();
    int row = blockIdx.x * 64 + (threadIdx.x >> 2);
    int c0 = (threadIdx.x & 3) * 16;
    if (row >= N_NODES) return;
    float acc[16];
#pragma unroll
    for (int j = 0; j < 16; ++j) acc[j] = b[c0 + j];
    const float4* xr = (const float4*)(x + (size_t)row * FDIM);
    for (int k4 = 0; k4 < FDIM / 4; ++k4) {
        float4 xv = xr[k4];
        const float* wr = Ws + (k4 * 4) * HID + c0;
#pragma unroll
        for (int j = 0; j < 16; ++j) acc[j] = fmaf(xv.x, wr[j], acc[j]);
#pragma unroll
        for (int j = 0; j < 16; ++j) acc[j] = fmaf(xv.y, wr[HID + j], acc[j]);
#pragma unroll
        for (int j = 0; j < 16; ++j) acc[j] = fmaf(xv.z, wr[2 * HID + j], acc[j]);
#pragma unroll
        for (int j = 0; j < 16; ++j) acc[j] = fmaf(xv.w, wr[3 * HID + j], acc[j]);
    }
    float* hr = h + (size_t)row * HID + c0;
#pragma unroll
    for (int j = 0; j < 16; ++j) hr[j] = acc[j];
}

__global__ void k_convmm(const float* __restrict__ h, const float* __restrict__ W,
                         const float* __restrict__ dis, __hip_bfloat16* __restrict__ hWs) {
    __shared__ float Ws[HID * HID];
    for (int idx = threadIdx.x; idx < HID * HID; idx += 256) Ws[idx] = W[idx];
    __syncthreads();
    int row = blockIdx.x * 64 + (threadIdx.x >> 2);
    int c0 = (threadIdx.x & 3) * 16;
    if (row >= N_NODES) return;
    float acc[16] = {0.f, 0.f, 0.f, 0.f, 0.f, 0.f, 0.f, 0.f,
                     0.f, 0.f, 0.f, 0.f, 0.f, 0.f, 0.f, 0.f};
    const float4* hr = (const float4*)(h + (size_t)row * HID);
    for (int k4 = 0; k4 < HID / 4; ++k4) {
        float4 hv = hr[k4];
        const float* wr = Ws + (k4 * 4) * HID + c0;
#pragma unroll
        for (int j = 0; j < 16; ++j) acc[j] = fmaf(hv.x, wr[j], acc[j]);
#pragma unroll
        for (int j = 0; j < 16; ++j) acc[j] = fmaf(hv.y, wr[HID + j], acc[j]);
#pragma unroll
        for (int j = 0; j < 16; ++j) acc[j] = fmaf(hv.z, wr[2 * HID + j], acc[j]);
#pragma unroll
        for (int j = 0; j < 16; ++j) acc[j] = fmaf(hv.w, wr[3 * HID + j], acc[j]);
    }
    float d = dis[row];
    __hip_bfloat16* o = hWs + (size_t)row * HID + c0;
#pragma unroll
    for (int j = 0; j < 16; ++j) o[j] = __float2bfloat16(d * acc[j]);
}

// ---------------- hash propagation (gather over CSR, unroll-8) ----------------

__global__ void k_hll(const int* __restrict__ offsets, const int* __restrict__ csr,
                      const uint* __restrict__ hin, uint* __restrict__ hout_p,
                      float* __restrict__ hout_f, float* __restrict__ cards, int kcol) {
    int node = blockIdx.x * 16 + (threadIdx.x >> 4);
    int q = threadIdx.x & 15;
    if (node >= N_NODES) return;
    int s = offsets[node], e = offsets[node + 1];
    uint m0 = 0, m1 = 0, m2 = 0, m3 = 0;
#define HLL_ACC(vv) do { uint _v = (vv); \
        m0 = max(m0, _v & 0xFFu); m1 = max(m1, (_v >> 8) & 0xFFu); \
        m2 = max(m2, (_v >> 16) & 0xFFu); m3 = max(m3, _v >> 24); } while (0)
    int p = s;
    for (; p + 8 <= e; p += 8) {
        int j0 = csr[p], j1 = csr[p + 1], j2 = csr[p + 2], j3 = csr[p + 3];
        int j4 = csr[p + 4], j5 = csr[p + 5], j6 = csr[p + 6], j7 = csr[p + 7];
        uint a0 = hin[(size_t)j0 * 16 + q];
        uint a1 = hin[(size_t)j1 * 16 + q];
        uint a2 = hin[(size_t)j2 * 16 + q];
        uint a3 = hin[(size_t)j3 * 16 + q];
        uint a4 = hin[(size_t)j4 * 16 + q];
        uint a5 = hin[(size_t)j5 * 16 + q];
        uint a6 = hin[(size_t)j6 * 16 + q];
        uint a7 = hin[(size_t)j7 * 16 + q];
        HLL_ACC(a0); HLL_ACC(a1); HLL_ACC(a2); HLL_ACC(a3);
        HLL_ACC(a4); HLL_ACC(a5); HLL_ACC(a6); HLL_ACC(a7);
    }
    for (; p < e; ++p) HLL_ACC(hin[(size_t)csr[p] * 16 + q]);
#undef HLL_ACC
    if (hout_p) hout_p[(size_t)node * 16 + q] = m0 | (m1 << 8) | (m2 << 16) | (m3 << 24);
    if (hout_f) {
        float4 w = {(float)m0, (float)m1, (float)m2, (float)m3};
        *(float4*)(hout_f + (size_t)node * HLLM + 4 * q) = w;
    }
    float v = exp2f(-(float)m0) + exp2f(-(float)m1) + exp2f(-(float)m2) + exp2f(-(float)m3);
    v += __shfl_xor(v, 1); v += __shfl_xor(v, 2);
    v += __shfl_xor(v, 4); v += __shfl_xor(v, 8);
    if (q == 0) {
        const float alphamm = (float)(0.7213 / (1.0 + 1.079 / 64.0) * 64.0 * 64.0);
        cards[(size_t)node * 2 + kcol] = alphamm / v;
    }
}

__global__ void k_mh(const int* __restrict__ offsets, const int* __restrict__ csr,
                     const uint* __restrict__ mhin, uint* __restrict__ out_p,
                     float* __restrict__ out_f) {
    int node = blockIdx.x * 4 + (threadIdx.x >> 6);
    int l = threadIdx.x & 63;
    if (node >= N_NODES) return;
    int s = offsets[node], e = offsets[node + 1];
    uint mn0 = 0xFFFFu, mn1 = 0xFFFFu, mn2 = 0xFFFFu, mn3 = 0xFFFFu;
    int p = s;
    for (; p + 8 <= e; p += 8) {
        int j0 = csr[p], j1 = csr[p + 1], j2 = csr[p + 2], j3 = csr[p + 3];
        int j4 = csr[p + 4], j5 = csr[p + 5], j6 = csr[p + 6], j7 = csr[p + 7];
        uint a0 = mhin[(size_t)j0 * 64 + l];
        uint a1 = mhin[(size_t)j1 * 64 + l];
        uint a2 = mhin[(size_t)j2 * 64 + l];
        uint a3 = mhin[(size_t)j3 * 64 + l];
        uint a4 = mhin[(size_t)j4 * 64 + l];
        uint a5 = mhin[(size_t)j5 * 64 + l];
        uint a6 = mhin[(size_t)j6 * 64 + l];
        uint a7 = mhin[(size_t)j7 * 64 + l];
        mn0 = min(mn0, min(a0 & 0xFFFFu, a1 & 0xFFFFu));
        mn1 = min(mn1, min(a0 >> 16, a1 >> 16));
        mn2 = min(mn2, min(a2 & 0xFFFFu, a3 & 0xFFFFu));
        mn3 = min(mn3, min(a2 >> 16, a3 >> 16));
        mn0 = min(mn0, min(a4 & 0xFFFFu, a5 & 0xFFFFu));
        mn1 = min(mn1, min(a4 >> 16, a5 >> 16));
        mn2 = min(mn2, min(a6 & 0xFFFFu, a7 & 0xFFFFu));
        mn3 = min(mn3, min(a6 >> 16, a7 >> 16));
    }
    for (; p < e; ++p) {
        uint a = mhin[(size_t)csr[p] * 64 + l];
        mn0 = min(mn0, a & 0xFFFFu); mn1 = min(mn1, a >> 16);
    }
    mn0 = min(mn0, mn2); mn1 = min(mn1, mn3);
    if (out_p) {
        out_p[(size_t)node * 64 + l] = mn0 | (mn1 << 16);
    } else {
        float2 w;
        w.x = __uint_as_float(mn0 << 16);
        w.y = __uint_as_float(mn1 << 16);
        *(float2*)(out_f + (size_t)node * NPERM + 2 * l) = w;
    }
}

__global__ void k_agg(const int* __restrict__ offsets, const int* __restrict__ csr,
                      const __hip_bfloat16* __restrict__ hWs, const float* __restrict__ dis,
                      const float* __restrict__ b, const float* __restrict__ h_in,
                      float* __restrict__ h_out) {
    int node = blockIdx.x * 4 + (threadIdx.x >> 6);
    int c = threadIdx.x & 63;
    if (node >= N_NODES) return;
    int s = offsets[node], e = offsets[node + 1];
    const unsigned short* hw = (const unsigned short*)hWs;
    float acc0 = 0.f, acc1 = 0.f;
    int p = s;
    for (; p + 8 <= e; p += 8) {
        int j0 = csr[p], j1 = csr[p + 1], j2 = csr[p + 2], j3 = csr[p + 3];
        int j4 = csr[p + 4], j5 = csr[p + 5], j6 = csr[p + 6], j7 = csr[p + 7];
        uint a0 = hw[(size_t)j0 * HID + c];
        uint a1 = hw[(size_t)j1 * HID + c];
        uint a2 = hw[(size_t)j2 * HID + c];
        uint a3 = hw[(size_t)j3 * HID + c];
        uint a4 = hw[(size_t)j4 * HID + c];
        uint a5 = hw[(size_t)j5 * HID + c];
        uint a6 = hw[(size_t)j6 * HID + c];
        uint a7 = hw[(size_t)j7 * HID + c];
        acc0 += __uint_as_float(a0 << 16) + __uint_as_float(a1 << 16)
              + __uint_as_float(a2 << 16) + __uint_as_float(a3 << 16);
        acc1 += __uint_as_float(a4 << 16) + __uint_as_float(a5 << 16)
              + __uint_as_float(a6 << 16) + __uint_as_float(a7 << 16);
    }
    for (; p < e; ++p)
        acc0 += __uint_as_float((uint)hw[(size_t)csr[p] * HID + c] << 16);
    float acc = acc0 + acc1;
    h_out[(size_t)node * HID + c] = h_in[(size_t)node * HID + c] + b[c] + dis[node] * acc;
}

// ---------------- driver ----------------

static inline char* align256(char* p) {
    return (char*)(((uintptr_t)p + 255) & ~(uintptr_t)255);
}

extern "C" void kernel_launch(void* const* d_in, const int* in_sizes, int n_in,
                              void* d_out, int out_size, void* d_ws, size_t ws_size,
                              hipStream_t stream) {
    const float* x       = (const float*)d_in[0];
    const int*   ei      = (const int*)d_in[1];
    const int*   mh0     = (const int*)d_in[2];
    const int*   hll0    = (const int*)d_in[3];
    const float* W_enc   = (const float*)d_in[4];
    const float* b_enc   = (const float*)d_in[5];
    const float* W_convs = (const float*)d_in[6];
    const float* b_convs = (const float*)d_in[7];

    float* out       = (float*)d_out;
    float* out_h     = out;
    float* out_cards = out + (size_t)N_NODES * HID;
    float* out_mh    = out_cards + (size_t)N_NODES * 2;
    float* out_hll   = out_mh + (size_t)N_NODES * NPERM;

    char* w = (char*)d_ws;
    int*   bktcnt  = (int*)w;   w = align256(w + (size_t)NBUCK * 4);
    int*   gbase   = (int*)w;   w = align256(w + (size_t)NBUCK * 4);
    int*   gcur    = (int*)w;   w = align256(w + (size_t)NBUCK * 4);
    int*   offsets = (int*)w;   w = align256(w + (size_t)(N_NODES + 1) * 4);
    float* dis     = (float*)w; w = align256(w + (size_t)N_NODES * 4);
    int*   csr     = (int*)w;   w = align256(w + (size_t)(N_EDGES + N_NODES) * 4);
    uint*  mhp0    = (uint*)w;  w = align256(w + (size_t)N_NODES * 64 * 4);
    uint*  mhA     = (uint*)w;  w = align256(w + (size_t)N_NODES * 64 * 4);
    uint*  hp0     = (uint*)w;  w = align256(w + (size_t)N_NODES * 16 * 4);
    uint*  hllA    = (uint*)w;  w = align256(w + (size_t)N_NODES * 16 * 4);
    float* h_cur   = (float*)w; w = align256(w + (size_t)N_NODES * HID * 4);
    __hip_bfloat16* hWs = (__hip_bfloat16*)w;
    uint*  ebuf    = mhA;  // build-phase only; mhA first written after k_csr consumed ebuf

    const int* src = ei;
    const int* dst = ei + N_EDGES;

    hipMemsetAsync(bktcnt, 0, (size_t)NBUCK * 4, stream);
    k_prep<<<MH_BLOCKS + HLL_BLOCKS + HIST_BLOCKS, 256, 0, stream>>>(mh0, mhp0, hll0, hp0, dst, bktcnt);
    k_bktscan<<<1, 256, 0, stream>>>(bktcnt, gbase, gcur, offsets);
    k_scatter<<<SCAT_BLOCKS, 256, 0, stream>>>(src, dst, gcur, ebuf);
    k_csr<<<NBUCK, 256, 0, stream>>>(ebuf, gbase, bktcnt, offsets, dis, csr);
    k_encoder<<<(N_NODES + 63) / 64, 256, 0, stream>>>(x, W_enc, b_enc, h_cur);

    // ---- hop 0 ----
    k_hll<<<(N_NODES + 15) / 16, 256, 0, stream>>>(offsets, csr, hp0, hllA, nullptr, out_cards, 0);
    k_mh<<<(N_NODES + 3) / 4, 256, 0, stream>>>(offsets, csr, mhp0, mhA, nullptr);
    k_convmm<<<(N_NODES + 63) / 64, 256, 0, stream>>>(h_cur, W_convs, dis, hWs);
    k_agg<<<(N_NODES + 3) / 4, 256, 0, stream>>>(offsets, csr, hWs, dis, b_convs, h_cur, h_cur);

    // ---- hop 1 ----
    k_hll<<<(N_NODES + 15) / 16, 256, 0, stream>>>(offsets, csr, hllA, nullptr, out_hll, out_cards, 1);
    k_mh<<<(N_NODES + 3) / 4, 256, 0, stream>>>(offsets, csr, mhA, nullptr, out_mh);
    k_convmm<<<(N_NODES + 63) / 64, 256, 0, stream>>>(h_cur, W_convs + HID * HID, dis, hWs);
    k_agg<<<(N_NODES + 3) / 4, 256, 0, stream>>>(offsets, csr, hWs, dis, b_convs + HID, h_cur, out_h);
}